// Round 9
// baseline (695.991 us; speedup 1.0000x reference)
//
#include <hip/hip_runtime.h>
#include <cstdint>
#include <cstddef>

#define NN 4096
#define TOPK_ 30
#define BN_TOT 8192          // B*N
#define M_TOT 245760         // B*N*TOPK
#define KP 448               // padded EDGE_IN (446 -> 448)
#define HSTRIDE 136          // hs leading dim (128 + 8 pad)
#define EF 128
#define BR 32                // edges (rows) per mega block

typedef unsigned short u16;
typedef unsigned int u32;
typedef __attribute__((ext_vector_type(8))) short bf16x8;
typedef __attribute__((ext_vector_type(4))) float f32x4;

__device__ __forceinline__ float b2f(u16 u){ return __uint_as_float(((u32)u)<<16); }
__device__ __forceinline__ u16 f2b(float f){
  u32 u = __float_as_uint(f);
  return (u16)((u + 0x7FFFu + ((u>>16)&1u)) >> 16);   // RNE
}
__device__ __forceinline__ float ldf(const void* p, long i, int fl){
  return fl ? ((const float*)p)[i] : b2f(((const u16*)p)[i]);
}
__device__ __forceinline__ int is_f32_flag(const u16* mask){
  return (((const u32*)mask)[0] == 0x3F800000u) ? 1 : 0;   // mask is all-ones
}
__device__ __forceinline__ void norm3(float x,float y,float z,float&ox,float&oy,float&oz){
  float n = sqrtf(x*x+y*y+z*z); n = fmaxf(n, 1e-12f);
  ox=x/n; oy=y/n; oz=z/n;
}
__device__ __forceinline__ float sgn(float x){ return x>0.f?1.f:(x<0.f?-1.f:0.f); }
// branch-free gelu: erf via A&S 7.1.26 (|err| < 1.5e-7, invisible under bf16)
__device__ __forceinline__ float gelu_fast(float x){
  float y = 0.70710678118654752440f * x;
  float s = fabsf(y);
  float t = __builtin_amdgcn_rcpf(fmaf(0.3275911f, s, 1.0f));
  float p = fmaf(fmaf(fmaf(fmaf(1.061405429f, t, -1.453152027f), t, 1.421413741f), t,
                 -0.284496736f), t, 0.254829592f);
  float e = __expf(-y*y);
  float erfs = fmaf(-p*t, e, 1.0f);            // erf(|y|)
  float erfy = (x >= 0.f) ? erfs : -erfs;
  float hx = 0.5f*x;
  return fmaf(hx, erfy, hx);
}
// packed f32->bf16 RNE; low half = first arg
__device__ __forceinline__ u32 pk_bf16(float lo, float hi){
  u32 r;
  asm("v_cvt_pk_bf16_f32 %0, %1, %2" : "=v"(r) : "v"(lo), "v"(hi));
  return r;
}
// load a 16-element row (bf16 or f32) with aligned vector loads; static unpack
__device__ __forceinline__ void ld16(const void* p, int row, int fl, float* o){
  if (fl) {
    const float4* q = (const float4*)((const float*)p + (long)row*16);
    float4 a=q[0], b=q[1], c=q[2], d=q[3];
    o[0]=a.x; o[1]=a.y; o[2]=a.z; o[3]=a.w;
    o[4]=b.x; o[5]=b.y; o[6]=b.z; o[7]=b.w;
    o[8]=c.x; o[9]=c.y; o[10]=c.z; o[11]=c.w;
    o[12]=d.x; o[13]=d.y; o[14]=d.z; o[15]=d.w;
  } else {
    const uint4* q = (const uint4*)((const u16*)p + (long)row*16);
    uint4 a=q[0], b=q[1];
    o[0]=__uint_as_float(a.x<<16);  o[1]=__uint_as_float(a.x&0xFFFF0000u);
    o[2]=__uint_as_float(a.y<<16);  o[3]=__uint_as_float(a.y&0xFFFF0000u);
    o[4]=__uint_as_float(a.z<<16);  o[5]=__uint_as_float(a.z&0xFFFF0000u);
    o[6]=__uint_as_float(a.w<<16);  o[7]=__uint_as_float(a.w&0xFFFF0000u);
    o[8]=__uint_as_float(b.x<<16);  o[9]=__uint_as_float(b.x&0xFFFF0000u);
    o[10]=__uint_as_float(b.y<<16); o[11]=__uint_as_float(b.y&0xFFFF0000u);
    o[12]=__uint_as_float(b.z<<16); o[13]=__uint_as_float(b.z&0xFFFF0000u);
    o[14]=__uint_as_float(b.w<<16); o[15]=__uint_as_float(b.w&0xFFFF0000u);
  }
}

// ---------------- prep: ca, lf, W1P/W2P frag-packed (source-major coalesced
// reads), b1p/b2p, Fp[8192][24] f32, wsc consts
__global__ __launch_bounds__(256) void prep_kernel(
    const void* __restrict__ X, const u16* __restrict__ mask,
    const void* __restrict__ mask_atoms,
    const void* __restrict__ means, const void* __restrict__ stds,
    const void* __restrict__ mul_w, const void* __restrict__ bias_w,
    const void* __restrict__ W1, const void* __restrict__ b1,
    const void* __restrict__ W2, const void* __restrict__ b2,
    float* __restrict__ ca, float* __restrict__ lf,
    u16* __restrict__ W1P, u16* __restrict__ W2P,
    float* __restrict__ b1p, float* __restrict__ b2p,
    float* __restrict__ Fp, float* __restrict__ wsc)
{
  const int fl = is_f32_flag(mask);
  int idx = blockIdx.x*256 + threadIdx.x;
  if (idx < BN_TOT) {
    int i = idx & (NN-1);
    float xr[15];
    #pragma unroll
    for (int v = 0; v < 15; ++v) xr[v] = ldf(X, (long)idx*15+v, fl);
    float cax = xr[3], cay = xr[4], caz = xr[5];
    ca[idx*4+0]=cax; ca[idx*4+1]=cay; ca[idx*4+2]=caz; ca[idx*4+3]=0.f;
    {
      float mres = ldf(mask, idx, fl);
      float m0 = ldf(mask_atoms,(long)idx*5+0,fl), m1 = ldf(mask_atoms,(long)idx*5+1,fl);
      float m2 = ldf(mask_atoms,(long)idx*5+2,fl), m3 = ldf(mask_atoms,(long)idx*5+3,fl);
      float m4 = ldf(mask_atoms,(long)idx*5+4,fl);
      float4* F4 = (float4*)(Fp + (long)idx*24);
      F4[0] = make_float4(xr[0],xr[1],xr[2],xr[3]);
      F4[1] = make_float4(xr[4],xr[5],xr[6],xr[7]);
      F4[2] = make_float4(xr[8],xr[9],xr[10],xr[11]);
      F4[3] = make_float4(xr[12],xr[13],xr[14],mres);
      F4[4] = make_float4(m0,m1,m2,m3);
      F4[5] = make_float4(m4,0.f,0.f,0.f);
    }
    float bx,by,bz,nx,ny,nz;
    if (i < NN-1) {
      float uix,uiy,uiz;
      if (i==0) { norm3(1.f,1.f,1.f,uix,uiy,uiz); }
      else {
        float px=ldf(X,(long)(idx-1)*15+3,fl), py=ldf(X,(long)(idx-1)*15+4,fl), pz=ldf(X,(long)(idx-1)*15+5,fl);
        norm3(cax-px, cay-py, caz-pz, uix,uiy,uiz);
      }
      float qx=ldf(X,(long)(idx+1)*15+3,fl), qy=ldf(X,(long)(idx+1)*15+4,fl), qz=ldf(X,(long)(idx+1)*15+5,fl);
      float vx,vy,vz; norm3(qx-cax, qy-cay, qz-caz, vx,vy,vz);
      norm3(uix-vx, uiy-vy, uiz-vz, bx,by,bz);
      norm3(uiy*vz-uiz*vy, uiz*vx-uix*vz, uix*vy-uiy*vx, nx,ny,nz);
    } else {
      norm3(1.f,1.f,1.f,bx,by,bz); nx=bx; ny=by; nz=bz;
    }
    float cx = by*nz - bz*ny, cy = bz*nx - bx*nz, cz = bx*ny - by*nx;
    float* L = lf + (size_t)idx*12;
    L[0]=bx;L[1]=by;L[2]=bz;L[3]=nx;L[4]=ny;L[5]=nz;L[6]=cx;L[7]=cy;L[8]=cz;
    return;
  }
  int r1 = idx - BN_TOT;
  if (r1 < 229376) {                 // W1P; r1 = k*512 + n : reads coalesced
    int k = r1 >> 9, n = r1 & 511;
    u16 v = (n < 446 && k < 446) ? (fl ? f2b(((const float*)W1)[(long)k*446 + n])
                                       : ((const u16*)W1)[(long)k*446 + n]) : (u16)0;
    int frag = (n >> 4)*14 + (k >> 5);
    int li = ((n & 15) + 16*((k & 31) >> 3))*8 + (k & 7);
    W1P[(frag << 9) + li] = v;
    return;
  }
  int r2 = r1 - 229376;
  if (r2 < 65536) {                  // W2P; r2 = k*128 + n : reads coalesced
    int k = r2 >> 7, n = r2 & 127;
    u16 v = (k < 446) ? (fl ? f2b(((const float*)W2)[(long)k*128 + n])
                            : ((const u16*)W2)[(long)k*128 + n]) : (u16)0;
    int frag = (n >> 4)*16 + (k >> 5);
    int li = ((n & 15) + 16*((k & 31) >> 3))*8 + (k & 7);
    W2P[(frag << 9) + li] = v;
    return;
  }
  int r3 = r2 - 65536;
  if (r3 < 512) { b1p[r3] = (r3<446)? ldf(b1, r3, fl) : 0.f; return; }
  int r4 = r3 - 512;
  if (r4 < 128) { b2p[r4] = ldf(b2, r4, fl); return; }
  int r5 = r4 - 128;
  if (r5 < 16) {
    float sd = fabsf(ldf(stds, r5, fl)) + 0.01f;
    float ri = 1.0f / sd;
    wsc[r5] = ldf(means, r5, fl);
    wsc[16 + r5] = ri;
    wsc[32 + r5] = 0.3989422804014327f * ri;
    return;
  }
  if (r5 < 41) { wsc[48 + (r5-16)] = ldf(mul_w, r5-16, fl); return; }
  if (r5 < 66) { wsc[73 + (r5-41)] = ldf(bias_w, r5-41, fl); }
}

// ---------------- knn v3 (unchanged): row-major stride-65 keys, wave-parallel
// rescan; exact numpy f32 arithmetic, stable tie-break.
__global__ __launch_bounds__(64) void knn_kernel(const float4* __restrict__ ca,
                                                 int* __restrict__ eidx)
{
#pragma clang fp contract(off)
  __shared__ u32 keys[64*65];
  int bi = blockIdx.x;
  int lane = threadIdx.x;
  int b = bi >> 12;
  const float4 ci = ca[bi];
  const float4* cab = ca + (b<<12);
  u32 mind = 0xFFFFFFFFu; int minj = 1<<30;
  for (int c = 0; c < 64; ++c) {
    int j = (c<<6) | lane;
    float4 cj = cab[j];
    float dx = cj.x-ci.x, dy = cj.y-ci.y, dz = cj.z-ci.z;
    float ss = dx*dx;
    ss = ss + dy*dy;
    ss = ss + dz*dz;
    float d = sqrtf(ss + 1e-6f);
    u32 db = __float_as_uint(d);
    keys[lane*65 + c] = db;
    if (db < mind) { mind = db; minj = j; }
  }
  __syncthreads();
  for (int r = 0; r < TOPK_; ++r) {
    u32 wd = mind; int wj = minj;
    #pragma unroll
    for (int off = 32; off; off >>= 1) {
      u32 od = __shfl_xor(wd, off, 64);
      int oj = __shfl_xor(wj, off, 64);
      if (od < wd || (od == wd && oj < wj)) { wd = od; wj = oj; }
    }
    if (lane == 0) eidx[bi*TOPK_ + r] = wj;
    int wl = wj & 63;
    if (lane == wl) keys[wl*65 + (wj>>6)] = 0xFFFFFFFFu;
    __syncthreads();
    u32 kv = keys[wl*65 + lane];
    int kj = (lane<<6)|wl;
    #pragma unroll
    for (int off = 32; off; off >>= 1) {
      u32 od = __shfl_xor(kv, off, 64);
      int oj = __shfl_xor(kj, off, 64);
      if (od < kv || (od == kv && oj < kj)) { kv = od; kj = oj; }
    }
    if (lane == wl) { mind = kv; minj = kj; }
  }
}

// ---------------- mega v9: 32-edge tiles, 256 threads, LDS ~32.5KB -> 3-4
// blocks/CU = 12-16 waves/CU (r8 was 8: 2blk x 4w, same as r7's 1blk x 8w —
// the split added no TLP). Waves are COLUMN slices: each wave = all 32 rows
// x 32 output cols, so W1P/W2P are still read exactly once per block and all
// accumulators stay <=32 VGPR (two-pass GEMM1). Occupancy doubles -> stall
// coverage (waves are ~80% stalled: 23k VALU-issue / 120k resident cycles).
__global__ __launch_bounds__(256,3) void mega_mlp(
    const float* __restrict__ Fp, const float* __restrict__ wsc,
    const u16* __restrict__ mask,
    const void* __restrict__ aa_pe, const void* __restrict__ relpos, const void* __restrict__ mask_emb,
    const int* __restrict__ aa, const int* __restrict__ ridx, const int* __restrict__ chains,
    const int* __restrict__ eidx, const float* __restrict__ ca, const float* __restrict__ lf,
    const u16* __restrict__ W1P, const u16* __restrict__ W2P,
    const float* __restrict__ b1p, const float* __restrict__ b2p,
    void* __restrict__ C)
{
  __shared__ __align__(16) u16 Et[BR*448];    // 28672 B; hs dbuf overlays after GEMM1
  __shared__ float Dabs[BR][29];              // 3712 B
  __shared__ float maA[BR];                   // 128 B
  const int fl = is_f32_flag(mask);
  int tid = threadIdx.x;
  int lane = tid & 63, wave = tid >> 6;       // wave = column slice 0..3
  int rowBase = blockIdx.x * BR;

  // ---- F1: xg for 25 atom pairs; 8 threads/edge, thread q handles a=q (q<5)
  {
    int eo = tid >> 3, q = tid & 7;
    int e = rowBase + eo;
    int bi = (int)((unsigned)e / 30u);
    int k = e - bi*30;
    int bj = ((bi >> 12) << 12) + eidx[bi*TOPK_ + k];
    const float* Fi = Fp + (long)bi*24;
    const float* Fj = Fp + (long)bj*24;
    if (q == 1) maA[eo] = Fi[15] * Fj[15];
    if (q < 5) {
      float Xi[15];
      {
        const float4* F4 = (const float4*)Fi;
        float4 A=F4[0], B=F4[1], Cc=F4[2], D=F4[3];
        Xi[0]=A.x;Xi[1]=A.y;Xi[2]=A.z;Xi[3]=A.w;
        Xi[4]=B.x;Xi[5]=B.y;Xi[6]=B.z;Xi[7]=B.w;
        Xi[8]=Cc.x;Xi[9]=Cc.y;Xi[10]=Cc.z;Xi[11]=Cc.w;
        Xi[12]=D.x;Xi[13]=D.y;Xi[14]=D.z;
      }
      float4 Mj = *(const float4*)(Fj + 16);
      float  Mj4 = Fj[20];
      int a = q;
      float xj0 = Fj[a*3+0], xj1 = Fj[a*3+1], xj2 = Fj[a*3+2];
      float mja = Fj[16+a];
      #pragma unroll
      for (int c = 0; c < 5; ++c) {
        float d0 = xj0 - Xi[c*3+0];
        float d1 = xj1 - Xi[c*3+1];
        float d2 = xj2 - Xi[c*3+2];
        float Dab = sqrtf(d0*d0 + d1*d1 + d2*d2 + 1e-12f);
        float mjc = (c==0)?Mj.x:(c==1)?Mj.y:(c==2)?Mj.z:(c==3)?Mj.w:Mj4;
        float mw = wsc[48 + a*5+c], bw = wsc[73 + a*5+c];
        Dabs[eo][a*5+c] = (mw*Dab + bw) * (mja * mjc);
      }
    }
  }

  // ---- F1b: per-row scalar features (cols 0-15, 416-447)
  if (tid < BR) {
    int eo = tid;
    int e = rowBase + eo;
    int bi = (int)((unsigned)e / 30u);
    int k = e - bi*30;
    int bj = ((bi >> 12) << 12) + eidx[bi*TOPK_ + k];
    float ma = Fp[(long)bi*24+15] * Fp[(long)bj*24+15];
    char* rowB = (char*)Et + eo*896;
    int xr = (eo & 7) << 4;
    {
      int d = ridx[bi] - ridx[bj] + 32; d = d < 0 ? 0 : (d > 64 ? 64 : d);
      int ch = (chains[bi] == chains[bj]) ? 1 : 0;
      float rp[16], me[16];
      ld16(relpos, d, fl, rp);
      ld16(mask_emb, ch, fl, me);
      uint4 wA, wB;
      wA.x = pk_bf16(rp[0]+me[0],  rp[1]+me[1]);
      wA.y = pk_bf16(rp[2]+me[2],  rp[3]+me[3]);
      wA.z = pk_bf16(rp[4]+me[4],  rp[5]+me[5]);
      wA.w = pk_bf16(rp[6]+me[6],  rp[7]+me[7]);
      wB.x = pk_bf16(rp[8]+me[8],  rp[9]+me[9]);
      wB.y = pk_bf16(rp[10]+me[10],rp[11]+me[11]);
      wB.z = pk_bf16(rp[12]+me[12],rp[13]+me[13]);
      wB.w = pk_bf16(rp[14]+me[14],rp[15]+me[15]);
      *(uint4*)(rowB + (0 ^ xr))  = wA;
      *(uint4*)(rowB + (16 ^ xr)) = wB;
    }
    float t0,t1,t2,q0,q1,q2,qw;
    {
      const float4* L4i = (const float4*)(lf + (size_t)bi*12);
      float4 a0=L4i[0], a1=L4i[1], a2=L4i[2];
      const float4* L4j = (const float4*)(lf + (size_t)bj*12);
      float4 b0=L4j[0], b1v=L4j[1], b2v=L4j[2];
      float4 cj4 = *(const float4*)(ca + bj*4);
      float4 ci4 = *(const float4*)(ca + bi*4);
      float dx = cj4.x-ci4.x, dy = cj4.y-ci4.y, dz = cj4.z-ci4.z;
      t0 = a0.x*dx + a0.y*dy + a0.z*dz;
      t1 = a0.w*dx + a1.x*dy + a1.y*dz;
      t2 = a1.z*dx + a1.w*dy + a2.x*dz;
      float tn = fmaxf(sqrtf(t0*t0+t1*t1+t2*t2), 1e-12f);
      t0 = t0/tn*ma; t1 = t1/tn*ma; t2 = t2/tn*ma;
      float R00 = a0.x*b0.x + a0.w*b0.w + a1.z*b1v.z;
      float R01 = a0.x*b0.y + a0.w*b1v.x + a1.z*b1v.w;
      float R02 = a0.x*b0.z + a0.w*b1v.y + a1.z*b2v.x;
      float R10 = a0.y*b0.x + a1.x*b0.w + a1.w*b1v.z;
      float R11 = a0.y*b0.y + a1.x*b1v.x + a1.w*b1v.w;
      float R12 = a0.y*b0.z + a1.x*b1v.y + a1.w*b2v.x;
      float R20 = a0.z*b0.x + a1.y*b0.w + a2.x*b1v.z;
      float R21 = a0.z*b0.y + a1.y*b1v.x + a2.x*b1v.w;
      float R22 = a0.z*b0.z + a1.y*b1v.y + a2.x*b2v.x;
      float m0 = 0.5f*sqrtf(fabsf(1.f+R00-R11-R22)+1e-12f);
      float m1 = 0.5f*sqrtf(fabsf(1.f-R00+R11-R22)+1e-12f);
      float m2 = 0.5f*sqrtf(fabsf(1.f-R00-R11+R22)+1e-12f);
      q0 = sgn(R21-R12)*m0; q1 = sgn(R02-R20)*m1; q2 = sgn(R10-R01)*m2;
      qw = 0.5f*sqrtf(fmaxf(1.f+R00+R11+R22, 0.f)+1e-12f);
      float qn = fmaxf(sqrtf(q0*q0+q1*q1+q2*q2+qw*qw), 1e-12f);
      q0 = q0/qn*ma; q1 = q1/qn*ma; q2 = q2/qn*ma; qw = qw/qn*ma;
    }
    {
      int aap = aa[bi]*22 + aa[bj];
      float av[16];
      ld16(aa_pe, aap, fl, av);
      uint4 w0, w1, w2, w3;
      w0.x = pk_bf16(t0, t1);  w0.y = pk_bf16(t2, q0);
      w0.z = pk_bf16(q1, q2);  w0.w = pk_bf16(qw, 1.f-2.f*fabsf(t0));
      w1.x = pk_bf16(1.f-2.f*fabsf(t1), 1.f-2.f*fabsf(t2));
      w1.y = pk_bf16(1.f-2.f*fabsf(q0), 1.f-2.f*fabsf(q1));
      w1.z = pk_bf16(1.f-2.f*fabsf(q2), 1.f-2.f*fabsf(qw));
      w1.w = pk_bf16(av[0]*ma, av[1]*ma);
      w2.x = pk_bf16(av[2]*ma, av[3]*ma);   w2.y = pk_bf16(av[4]*ma, av[5]*ma);
      w2.z = pk_bf16(av[6]*ma, av[7]*ma);   w2.w = pk_bf16(av[8]*ma, av[9]*ma);
      w3.x = pk_bf16(av[10]*ma, av[11]*ma); w3.y = pk_bf16(av[12]*ma, av[13]*ma);
      w3.z = pk_bf16(av[14]*ma, av[15]*ma); w3.w = 0u;
      *(uint4*)(rowB + (832 ^ xr)) = w0;
      *(uint4*)(rowB + (848 ^ xr)) = w1;
      *(uint4*)(rowB + (864 ^ xr)) = w2;
      *(uint4*)(rowB + (880 ^ xr)) = w3;
    }
  }
  __syncthreads();

  // ---- F2: RBF cols 16..415 (50 groups x 32 rows = 1600; 256 thr x 7)
  {
    float meanv[16], rinvv[16], coefv[16];
    {
      const float4* W4 = (const float4*)wsc;
      #pragma unroll
      for (int g = 0; g < 4; ++g) {
        float4 m = W4[g], r = W4[4+g], c = W4[8+g];
        meanv[g*4+0]=m.x; meanv[g*4+1]=m.y; meanv[g*4+2]=m.z; meanv[g*4+3]=m.w;
        rinvv[g*4+0]=r.x; rinvv[g*4+1]=r.y; rinvv[g*4+2]=r.z; rinvv[g*4+3]=r.w;
        coefv[g*4+0]=c.x; coefv[g*4+1]=c.y; coefv[g*4+2]=c.z; coefv[g*4+3]=c.w;
      }
    }
    #pragma unroll 1
    for (int i = 0; i < 7; ++i) {
      int G = tid + i*256;
      if (G < 1600) {
        int row = (int)((unsigned)G / 50u);
        int gp = G - row*50;
        float xg = Dabs[row][gp >> 1];
        float ma = maA[row];
        int odd = gp & 1;
        u32 w[4];
        #pragma unroll
        for (int j2 = 0; j2 < 4; ++j2) {
          float me0 = odd ? meanv[j2*2+8] : meanv[j2*2];
          float ri0 = odd ? rinvv[j2*2+8] : rinvv[j2*2];
          float co0 = odd ? coefv[j2*2+8] : coefv[j2*2];
          float me1 = odd ? meanv[j2*2+9] : meanv[j2*2+1];
          float ri1 = odd ? rinvv[j2*2+9] : rinvv[j2*2+1];
          float co1 = odd ? coefv[j2*2+9] : coefv[j2*2+1];
          float z0 = (xg - me0) * ri0;
          float z1 = (xg - me1) * ri1;
          float v0 = __expf(-0.5f*z0*z0) * co0 * ma;
          float v1 = __expf(-0.5f*z1*z1) * co1 * ma;
          w[j2] = pk_bf16(v0, v1);
        }
        uint4 W4o; W4o.x = w[0]; W4o.y = w[1]; W4o.z = w[2]; W4o.w = w[3];
        *(uint4*)((char*)Et + row*896 + ((32 + (gp<<4)) ^ ((row&7)<<4))) = W4o;
      }
    }
  }
  __syncthreads();                              // Et complete

  // ---- GEMM1 (two passes): wave = all 32 rows (r<2) x cols wave*32+cc*16
  // (cc<2) of each 128-col chunk; acc1h 32 VGPR, packed into hpk, dies.
  u32 hpk[4][2][2][2];          // [chunk][r][cc][pair]
  #define GEMM1_HALF(H) do {                                                      \
    f32x4 acc1h[2][2][2] = {};                                                    \
    _Pragma("unroll 1")                                                           \
    for (int t = 0; t < 7; ++t) {                                                 \
      bf16x8 af[2][2];                                                            \
      _Pragma("unroll")                                                           \
      for (int kk = 0; kk < 2; ++kk)                                              \
        _Pragma("unroll")                                                         \
        for (int r = 0; r < 2; ++r) {                                             \
          int row = r*16 + (lane&15);                                             \
          int s = kk*4 + (lane>>4);                                               \
          af[kk][r] = *(const bf16x8*)(Et + row*448 + t*64 + ((s ^ (row&7))<<3)); \
        }                                                                         \
      _Pragma("unroll")                                                           \
      for (int c = 0; c < 2; ++c) {                                               \
        bf16x8 bg[2][2];                                                          \
        _Pragma("unroll")                                                         \
        for (int cc = 0; cc < 2; ++cc)                                            \
          _Pragma("unroll")                                                       \
          for (int kk = 0; kk < 2; ++kk)                                          \
            bg[cc][kk] = *(const bf16x8*)(W1P +                                   \
              ((((2*(H)+c)*8 + wave*2 + cc)*14 + t*2 + kk) << 9) + lane*8);       \
        _Pragma("unroll")                                                         \
        for (int r = 0; r < 2; ++r)                                               \
          _Pragma("unroll")                                                       \
          for (int cc = 0; cc < 2; ++cc)                                          \
            _Pragma("unroll")                                                     \
            for (int kk = 0; kk < 2; ++kk)                                        \
              acc1h[c][r][cc] = __builtin_amdgcn_mfma_f32_16x16x32_bf16(          \
                  af[kk][r], bg[cc][kk], acc1h[c][r][cc], 0,0,0);                 \
      }                                                                           \
    }                                                                             \
    _Pragma("unroll")                                                             \
    for (int c = 0; c < 2; ++c)                                                   \
      _Pragma("unroll")                                                           \
      for (int r = 0; r < 2; ++r)                                                 \
        _Pragma("unroll")                                                         \
        for (int cc = 0; cc < 2; ++cc) {                                          \
          int col = wave*32 + cc*16 + (lane & 15);                                \
          float bv = b1p[(2*(H)+c)*128 + col];                                    \
          hpk[2*(H)+c][r][cc][0] = pk_bf16(gelu_fast(acc1h[c][r][cc][0]+bv),      \
                                           gelu_fast(acc1h[c][r][cc][1]+bv));     \
          hpk[2*(H)+c][r][cc][1] = pk_bf16(gelu_fast(acc1h[c][r][cc][2]+bv),      \
                                           gelu_fast(acc1h[c][r][cc][3]+bv));     \
        }                                                                         \
  } while(0)

  GEMM1_HALF(0);
  GEMM1_HALF(1);
  #undef GEMM1_HALF

  // ---- GEMM2: hs dbuf (32x136 x2 = 17408B) overlaid on Et
  u16* hs0 = Et;
  u16* hs1 = Et + BR*HSTRIDE;
  #define STORE_HS(cN, buf) do {                                                  \
    _Pragma("unroll")                                                             \
    for (int r = 0; r < 2; ++r) {                                                 \
      _Pragma("unroll")                                                           \
      for (int cc = 0; cc < 2; ++cc) {                                            \
        int col = wave*32 + cc*16 + (lane & 15);                                  \
        int row0 = r*16 + (lane>>4)*4;                                            \
        u32 p01 = hpk[cN][r][cc][0], p23 = hpk[cN][r][cc][1];                     \
        u16* hb_ = (buf) + row0*HSTRIDE + col;                                    \
        hb_[0]         = (u16)p01; hb_[HSTRIDE]   = (u16)(p01>>16);               \
        hb_[2*HSTRIDE] = (u16)p23; hb_[3*HSTRIDE] = (u16)(p23>>16);               \
      }                                                                           \
    }                                                                             \
  } while(0)

  f32x4 acc2[2][2] = {};
  __syncthreads();                        // GEMM1 Et reads done; region -> hs
  STORE_HS(0, hs0);
  __syncthreads();                        // hs(0) published
  #pragma unroll
  for (int c = 0; c < 4; ++c) {
    u16* hb = (c & 1) ? hs1 : hs0;
    u16* hn = (c & 1) ? hs0 : hs1;
    if (c < 3) STORE_HS(c+1, hn);         // overlaps MFMA(c)
    #pragma unroll
    for (int k2 = 0; k2 < 4; ++k2) {
      bf16x8 af2[2], bg2[2];
      #pragma unroll
      for (int r = 0; r < 2; ++r) {
        int row = r*16 + (lane&15);
        af2[r] = *(const bf16x8*)(hb + row*HSTRIDE + k2*32 + (lane>>4)*8);
      }
      #pragma unroll
      for (int cc = 0; cc < 2; ++cc)
        bg2[cc] = *(const bf16x8*)(W2P + ((((wave*2+cc)*16) + c*4 + k2) << 9) + lane*8);
      #pragma unroll
      for (int r = 0; r < 2; ++r)
        #pragma unroll
        for (int cc = 0; cc < 2; ++cc)
          acc2[r][cc] = __builtin_amdgcn_mfma_f32_16x16x32_bf16(af2[r], bg2[cc], acc2[r][cc], 0,0,0);
    }
    __syncthreads();
  }
  #undef STORE_HS

  const int f32out = fl;
  #pragma unroll
  for (int r = 0; r < 2; ++r) {
    #pragma unroll
    for (int cc = 0; cc < 2; ++cc) {
      int col = wave*32 + cc*16 + (lane & 15);
      float bv = b2p[col];
      #pragma unroll
      for (int g = 0; g < 4; ++g) {
        long row = (long)rowBase + r*16 + (lane>>4)*4 + g;
        float v = acc2[r][cc][g] + bv;
        long o = row*EF + col;
        if (f32out) ((float*)C)[o] = v;
        else        ((u16*)C)[o]  = f2b(v);
      }
    }
  }
}

extern "C" void kernel_launch(void* const* d_in, const int* in_sizes, int n_in,
                              void* d_out, int out_size, void* d_ws, size_t ws_size,
                              hipStream_t stream) {
  const void* X          = d_in[0];
  const u16* mask        = (const u16*)d_in[1];
  const void* mask_atoms = d_in[2];
  const void* means      = d_in[3];
  const void* stds       = d_in[4];
  const void* mul_w      = d_in[5];
  const void* bias_w     = d_in[6];
  const void* aa_pe      = d_in[7];
  const void* relpos     = d_in[8];
  const void* mask_emb   = d_in[9];
  const void* W1         = d_in[10];
  const void* b1         = d_in[11];
  const void* W2         = d_in[12];
  const void* b2         = d_in[13];
  const int* aa          = (const int*)d_in[14];
  const int* ridx        = (const int*)d_in[15];
  const int* chains      = (const int*)d_in[16];

  char* ws = (char*)d_ws;
  float* ca  = (float*)(ws + 0);           // 131072
  float* lf  = (float*)(ws + 131072);      // 393216
  int* eidx  = (int*)(ws + 524288);        // 983040
  u16* W1P   = (u16*)(ws + 1507328);       // 458752
  u16* W2P   = (u16*)(ws + 1966080);       // 131072
  float* b1p = (float*)(ws + 2097152);     // 2048
  float* b2p = (float*)(ws + 2099200);     // 512
  float* wsc = (float*)(ws + 2099712);     // 512 (98 used)
  float* Fp  = (float*)(ws + 2100224);     // 786432

  prep_kernel<<<1187, 256, 0, stream>>>(X, mask, mask_atoms, means, stds, mul_w, bias_w,
                                        W1, b1, W2, b2, ca, lf, W1P, W2P, b1p, b2p, Fp, wsc);
  knn_kernel<<<BN_TOT, 64, 0, stream>>>((const float4*)ca, eidx);
  mega_mlp<<<M_TOT/BR, 256, 0, stream>>>(Fp, wsc, mask,
                                         aa_pe, relpos, mask_emb, aa, ridx, chains,
                                         eidx, ca, lf, W1P, W2P, b1p, b2p, d_out);
}